// Round 1
// baseline (472.034 us; speedup 1.0000x reference)
//
#include <hip/hip_runtime.h>

typedef unsigned short u16;
typedef unsigned int   u32;
typedef float f32x4 __attribute__((ext_vector_type(4)));
typedef short s16x8 __attribute__((ext_vector_type(8)));

#define NB    65536
#define K1    512
#define N1    1152
#define G1D   384
#define K2    384
#define N2    48
#define G2D   16
#define NL    256

__device__ inline u16 f2bf(float f) {
  u32 u = __float_as_uint(f);
  u += 0x7fffu + ((u >> 16) & 1u);
  return (u16)(u >> 16);
}
__device__ inline float bf2f(u16 h) { return __uint_as_float(((u32)h) << 16); }
__device__ inline float sigmoidf_(float x) { return 1.0f / (1.0f + __expf(-x)); }
__device__ inline float tanhf_(float x) {
  float e = __expf(2.0f * fabsf(x));
  float t = 1.0f - 2.0f / (e + 1.0f);
  return copysignf(t, x);
}

// ---- prep: concat x1|x2 -> bf16 A (NB x 512) ----
__global__ void prep_a(const float* __restrict__ x1, const float* __restrict__ x2,
                       u16* __restrict__ Abf) {
  int t = blockIdx.x * 256 + threadIdx.x;   // 8 elems/thread
  int i = t * 8;
  int row = i >> 9, col = i & 511;
  const float* src = (col < 384) ? (x1 + row * 384 + col) : (x2 + row * 128 + (col - 384));
  float4 v0 = ((const float4*)src)[0];
  float4 v1 = ((const float4*)src)[1];
  union { uint4 v; u16 u[8]; } o;
  o.u[0] = f2bf(v0.x); o.u[1] = f2bf(v0.y); o.u[2] = f2bf(v0.z); o.u[3] = f2bf(v0.w);
  o.u[4] = f2bf(v1.x); o.u[5] = f2bf(v1.y); o.u[6] = f2bf(v1.z); o.u[7] = f2bf(v1.w);
  *(uint4*)(Abf + i) = o.v;
}

// ---- prep: transpose+cast weight w[K][N] -> wt[N][K] bf16 ----
__global__ void prep_wt(const float* __restrict__ w, u16* __restrict__ wt, int K, int N) {
  int n = blockIdx.x;
  int k0 = threadIdx.x * 8;
  if (k0 >= K) return;
  union { uint4 v; u16 u[8]; } o;
#pragma unroll
  for (int j = 0; j < 8; j++) o.u[j] = f2bf(w[(k0 + j) * N + n]);
  *(uint4*)(wt + n * K + k0) = o.v;
}

// ---- GEMM1: Xi(bf16 NB x 1152) = Abf(NB x 512) @ W1t(1152 x 512)^T ----
__global__ __launch_bounds__(256) void gemm1(const u16* __restrict__ A,
                                             const u16* __restrict__ Bt,
                                             u16* __restrict__ Xi) {
  __shared__ u16 As[128 * 32];
  __shared__ u16 Bs[128 * 32];
  const int tid = threadIdx.x;
  const int wave = tid >> 6, lane = tid & 63;
  const int quad = lane >> 4, l16 = lane & 15;
  const int mbase = blockIdx.x * 128;
  const int nbase = blockIdx.y * 128;
  const int wm = (wave & 1) * 64, wn = (wave >> 1) * 64;

  f32x4 acc[4][4];
#pragma unroll
  for (int i = 0; i < 4; i++)
#pragma unroll
    for (int j = 0; j < 4; j++)
#pragma unroll
      for (int r = 0; r < 4; r++) acc[i][j][r] = 0.0f;

  const int r0 = tid >> 2, kc = (tid & 3) * 8;
  const u16* Aptr = A + (long)(mbase + r0) * K1 + kc;
  const u16* Bptr = Bt + (long)(nbase + r0) * K1 + kc;

  for (int k0 = 0; k0 < K1; k0 += 32) {
    uint4 a0 = *(const uint4*)(Aptr + k0);
    uint4 a1 = *(const uint4*)(Aptr + 64 * K1 + k0);
    uint4 b0 = *(const uint4*)(Bptr + k0);
    uint4 b1 = *(const uint4*)(Bptr + 64 * K1 + k0);
    __syncthreads();
    *(uint4*)(&As[r0 * 32 + kc]) = a0;
    *(uint4*)(&As[(64 + r0) * 32 + kc]) = a1;
    *(uint4*)(&Bs[r0 * 32 + kc]) = b0;
    *(uint4*)(&Bs[(64 + r0) * 32 + kc]) = b1;
    __syncthreads();
    s16x8 af[4], bfr[4];
#pragma unroll
    for (int i = 0; i < 4; i++) {
      af[i]  = *(const s16x8*)(&As[(wm + i * 16 + l16) * 32 + quad * 8]);
      bfr[i] = *(const s16x8*)(&Bs[(wn + i * 16 + l16) * 32 + quad * 8]);
    }
#pragma unroll
    for (int mi = 0; mi < 4; mi++)
#pragma unroll
      for (int ni = 0; ni < 4; ni++)
        acc[mi][ni] = __builtin_amdgcn_mfma_f32_16x16x32_bf16(af[mi], bfr[ni], acc[mi][ni], 0, 0, 0);
  }

#pragma unroll
  for (int mi = 0; mi < 4; mi++) {
#pragma unroll
    for (int rr = 0; rr < 4; rr++) {
      int row = mbase + wm + mi * 16 + quad * 4 + rr;
      u16* orow = Xi + (long)row * N1 + nbase + wn;
#pragma unroll
      for (int ni = 0; ni < 4; ni++)
        orow[ni * 16 + l16] = f2bf(acc[mi][ni][rr]);
    }
  }
}

// ---- gate1: h1 = (1-z)*tanh(xh + b0h + r*b1h), z/r from sigmoid ----
__global__ void gate1(const u16* __restrict__ Xi, const float* __restrict__ bias,
                      u16* __restrict__ H1) {
  int t = blockIdx.x * 256 + threadIdx.x;  // NB*384/8 tasks
  int row = t / 48;
  int ug = (t - row * 48) * 8;
  const u16* xir = Xi + (long)row * N1;
  union { uint4 v; u16 u[8]; } uz, ur, uh, o;
  uz.v = *(const uint4*)(xir + ug);
  ur.v = *(const uint4*)(xir + 384 + ug);
  uh.v = *(const uint4*)(xir + 768 + ug);
#pragma unroll
  for (int j = 0; j < 8; j++) {
    int u = ug + j;
    float z  = sigmoidf_(bf2f(uz.u[j]) + bias[u] + bias[1152 + u]);
    float rg = sigmoidf_(bf2f(ur.u[j]) + bias[384 + u] + bias[1152 + 384 + u]);
    float hc = tanhf_(bf2f(uh.u[j]) + bias[768 + u] + rg * bias[1152 + 768 + u]);
    o.u[j] = f2bf((1.0f - z) * hc);
  }
  *(uint4*)(H1 + (long)row * G1D + ug) = o.v;
}

// ---- GEMM2 + gates fused: H2(f32 NB x 16) from H1 @ W2t^T ----
__global__ __launch_bounds__(256) void gemm2(const u16* __restrict__ H1b,
                                             const u16* __restrict__ W2t,
                                             const float* __restrict__ bias2,
                                             float* __restrict__ H2) {
  __shared__ u16 As[128 * 32];
  __shared__ u16 Bs[48 * 32];
  const int tid = threadIdx.x;
  const int wave = tid >> 6, lane = tid & 63;
  const int quad = lane >> 4, l16 = lane & 15;
  const int mbase = blockIdx.x * 128;

  f32x4 acc[2][3];
#pragma unroll
  for (int i = 0; i < 2; i++)
#pragma unroll
    for (int j = 0; j < 3; j++)
#pragma unroll
      for (int r = 0; r < 4; r++) acc[i][j][r] = 0.0f;

  const int r0 = tid >> 2, kc = (tid & 3) * 8;
  const u16* Aptr = H1b + (long)(mbase + r0) * K2 + kc;

  for (int k0 = 0; k0 < K2; k0 += 32) {
    uint4 a0 = *(const uint4*)(Aptr + k0);
    uint4 a1 = *(const uint4*)(Aptr + 64 * K2 + k0);
    uint4 bv;
    if (tid < 192) bv = *(const uint4*)(W2t + r0 * K2 + k0 + kc);
    __syncthreads();
    *(uint4*)(&As[r0 * 32 + kc]) = a0;
    *(uint4*)(&As[(64 + r0) * 32 + kc]) = a1;
    if (tid < 192) *(uint4*)(&Bs[r0 * 32 + kc]) = bv;
    __syncthreads();
    s16x8 af[2], bfr[3];
#pragma unroll
    for (int mi = 0; mi < 2; mi++)
      af[mi] = *(const s16x8*)(&As[(wave * 32 + mi * 16 + l16) * 32 + quad * 8]);
#pragma unroll
    for (int ni = 0; ni < 3; ni++)
      bfr[ni] = *(const s16x8*)(&Bs[(ni * 16 + l16) * 32 + quad * 8]);
#pragma unroll
    for (int mi = 0; mi < 2; mi++)
#pragma unroll
      for (int ni = 0; ni < 3; ni++)
        acc[mi][ni] = __builtin_amdgcn_mfma_f32_16x16x32_bf16(af[mi], bfr[ni], acc[mi][ni], 0, 0, 0);
  }

  const int u = l16;
  const float b0z = bias2[u],      b1z = bias2[48 + u];
  const float b0r = bias2[16 + u], b1r = bias2[64 + u];
  const float b0h = bias2[32 + u], b1h = bias2[80 + u];
#pragma unroll
  for (int mi = 0; mi < 2; mi++) {
#pragma unroll
    for (int rr = 0; rr < 4; rr++) {
      int row = mbase + wave * 32 + mi * 16 + quad * 4 + rr;
      float z  = sigmoidf_(acc[mi][0][rr] + b0z + b1z);
      float rg = sigmoidf_(acc[mi][1][rr] + b0r + b1r);
      float hc = tanhf_(acc[mi][2][rr] + b0h + rg * b1h);
      H2[row * 16 + u] = (1.0f - z) * hc;
    }
  }
}

// ---- FC + softmax: one wave per row ----
__global__ __launch_bounds__(256) void fc_softmax(const float* __restrict__ H2,
                                                  const float* __restrict__ w1,
                                                  const float* __restrict__ fb1,
                                                  const float* __restrict__ w2,
                                                  const float* __restrict__ fb2,
                                                  const float* __restrict__ g1,
                                                  const float* __restrict__ g2,
                                                  float* __restrict__ out) {
  int row = blockIdx.x * 4 + (threadIdx.x >> 6);
  int lane = threadIdx.x & 63;
  const float* h2r = H2 + row * 16;
  float h[16];
#pragma unroll
  for (int uu = 0; uu < 16; uu++) h[uu] = h2r[uu];
  float e[4];
  float mx = -1e30f;
#pragma unroll
  for (int i = 0; i < 4; i++) {
    int c = i * 64 + lane;
    float a1 = fb1[c], a2 = fb2[c];
#pragma unroll
    for (int uu = 0; uu < 16; uu++) {
      a1 = fmaf(h[uu], w1[uu * 256 + c], a1);
      a2 = fmaf(h[uu], w2[uu * 256 + c], a2);
    }
    float d = g1[c] * tanhf_(a1) + g2[c] * tanhf_(a2);
    e[i] = d;
    mx = fmaxf(mx, d);
  }
#pragma unroll
  for (int off = 32; off >= 1; off >>= 1) mx = fmaxf(mx, __shfl_xor(mx, off, 64));
  float s = 0.0f;
#pragma unroll
  for (int i = 0; i < 4; i++) { e[i] = __expf(e[i] - mx); s += e[i]; }
#pragma unroll
  for (int off = 32; off >= 1; off >>= 1) s += __shfl_xor(s, off, 64);
  float inv = 1.0f / s;
  float* orow = out + (long)row * 256;
#pragma unroll
  for (int i = 0; i < 4; i++) orow[i * 64 + lane] = e[i] * inv;
}

extern "C" void kernel_launch(void* const* d_in, const int* in_sizes, int n_in,
                              void* d_out, int out_size, void* d_ws, size_t ws_size,
                              hipStream_t stream) {
  const float* x1   = (const float*)d_in[0];
  const float* x2   = (const float*)d_in[1];
  const float* w1k  = (const float*)d_in[2];   // gru1_kernel (512 x 1152)
  const float* b1g  = (const float*)d_in[4];   // gru1_bias (2 x 1152)
  const float* w2k  = (const float*)d_in[5];   // gru2_kernel (384 x 48)
  const float* b2g  = (const float*)d_in[7];   // gru2_bias (2 x 48)
  const float* fcw1 = (const float*)d_in[8];
  const float* fcb1 = (const float*)d_in[9];
  const float* fcw2 = (const float*)d_in[10];
  const float* fcb2 = (const float*)d_in[11];
  const float* fcg1 = (const float*)d_in[12];
  const float* fcg2 = (const float*)d_in[13];
  float* out = (float*)d_out;

  char* ws = (char*)d_ws;
  u16* Abf = (u16*)(ws + 0);            // 65536*512*2   = 67108864
  u16* W1t = (u16*)(ws + 67108864);     // 1152*512*2    = 1179648
  u16* Xi  = (u16*)(ws + 68288512);     // 65536*1152*2  = 150994944
  u16* H1  = (u16*)(ws + 219283456);    // 65536*384*2   = 50331648
  u16* W2t = (u16*)(ws + 269615104);    // 48*384*2      = 36864
  float* H2 = (float*)(ws + 269651968); // 65536*16*4    = 4194304

  hipLaunchKernelGGL(prep_a, dim3(16384), dim3(256), 0, stream, x1, x2, Abf);
  hipLaunchKernelGGL(prep_wt, dim3(1152), dim3(64), 0, stream, w1k, W1t, 512, 1152);
  hipLaunchKernelGGL(prep_wt, dim3(48), dim3(64), 0, stream, w2k, W2t, 384, 48);
  hipLaunchKernelGGL(gemm1, dim3(512, 9), dim3(256), 0, stream, Abf, W1t, Xi);
  hipLaunchKernelGGL(gate1, dim3(12288), dim3(256), 0, stream, Xi, b1g, H1);
  hipLaunchKernelGGL(gemm2, dim3(512), dim3(256), 0, stream, H1, W2t, b2g, H2);
  hipLaunchKernelGGL(fc_softmax, dim3(16384), dim3(256), 0, stream, H2,
                     fcw1, fcb1, fcw2, fcb2, fcg1, fcg2, out);
}

// Round 2
// 469.969 us; speedup vs baseline: 1.0044x; 1.0044x over previous
//
#include <hip/hip_runtime.h>

typedef unsigned short u16;
typedef unsigned int   u32;
typedef float f32x4 __attribute__((ext_vector_type(4)));
typedef short s16x8 __attribute__((ext_vector_type(8)));

#define NB    65536
#define K1    512
#define N1    1152
#define G1D   384
#define K2    384
#define N2    48
#define G2D   16
#define NL    256

__device__ inline u16 f2bf(float f) {
  u32 u = __float_as_uint(f);
  u += 0x7fffu + ((u >> 16) & 1u);
  return (u16)(u >> 16);
}
__device__ inline float bf2f(u16 h) { return __uint_as_float(((u32)h) << 16); }
__device__ inline float sigmoidf_(float x) { return 1.0f / (1.0f + __expf(-x)); }
__device__ inline float tanhf_(float x) {
  float e = __expf(2.0f * fabsf(x));
  float t = 1.0f - 2.0f / (e + 1.0f);
  return copysignf(t, x);
}

// async global->LDS, 16B per lane; LDS dest must be wave-uniform base + lane*16
__device__ inline void gld16(const u16* g, u16* l) {
  __builtin_amdgcn_global_load_lds(
      (const __attribute__((address_space(1))) void*)g,
      (__attribute__((address_space(3))) void*)l, 16, 0, 0);
}

// ---- prep: concat x1|x2 -> bf16 A (NB x 512) ----
__global__ void prep_a(const float* __restrict__ x1, const float* __restrict__ x2,
                       u16* __restrict__ Abf) {
  int t = blockIdx.x * 256 + threadIdx.x;   // 8 elems/thread
  int i = t * 8;
  int row = i >> 9, col = i & 511;
  const float* src = (col < 384) ? (x1 + row * 384 + col) : (x2 + row * 128 + (col - 384));
  float4 v0 = ((const float4*)src)[0];
  float4 v1 = ((const float4*)src)[1];
  union { uint4 v; u16 u[8]; } o;
  o.u[0] = f2bf(v0.x); o.u[1] = f2bf(v0.y); o.u[2] = f2bf(v0.z); o.u[3] = f2bf(v0.w);
  o.u[4] = f2bf(v1.x); o.u[5] = f2bf(v1.y); o.u[6] = f2bf(v1.z); o.u[7] = f2bf(v1.w);
  *(uint4*)(Abf + i) = o.v;
}

// ---- prep: coalesced tile-transpose W1 [512][1152] f32 -> W1t [1152][512] bf16 ----
__global__ __launch_bounds__(256) void prep_wt1(const float* __restrict__ w,
                                                u16* __restrict__ wt) {
  __shared__ float tile[64][65];
  const int nt = blockIdx.x * 64;   // 18
  const int kt = blockIdx.y * 64;   // 8
  const int tr = threadIdx.x >> 4;
  const int tc = (threadIdx.x & 15) * 4;
#pragma unroll
  for (int p = 0; p < 4; p++) {
    int k = kt + p * 16 + tr;
    float4 v = *(const float4*)(w + (long)k * N1 + nt + tc);
    tile[p * 16 + tr][tc + 0] = v.x;
    tile[p * 16 + tr][tc + 1] = v.y;
    tile[p * 16 + tr][tc + 2] = v.z;
    tile[p * 16 + tr][tc + 3] = v.w;
  }
  __syncthreads();
  const int nl = threadIdx.x >> 3;        // 0..31
  const int kc = (threadIdx.x & 7) * 8;
#pragma unroll
  for (int p = 0; p < 2; p++) {
    int n = nl + p * 32;
    union { uint4 v; u16 u[8]; } o;
#pragma unroll
    for (int j = 0; j < 8; j++) o.u[j] = f2bf(tile[kc + j][n]);
    *(uint4*)(wt + (long)(nt + n) * K1 + kt + kc) = o.v;
  }
}

// ---- prep: small transpose+cast weight w[K][N] -> wt[N][K] bf16 (W2) ----
__global__ void prep_wt(const float* __restrict__ w, u16* __restrict__ wt, int K, int N) {
  int n = blockIdx.x;
  int k0 = threadIdx.x * 8;
  if (k0 >= K) return;
  union { uint4 v; u16 u[8]; } o;
#pragma unroll
  for (int j = 0; j < 8; j++) o.u[j] = f2bf(w[(k0 + j) * N + n]);
  *(uint4*)(wt + n * K + k0) = o.v;
}

// ---- GEMM1: Xi(bf16 NB x 1152) = Abf(NB x 512) @ W1t(1152 x 512)^T ----
// LDS layout (per 128x32 tile, two 64-row segments of 4096B):
//   chunk index within segment = r*4 + (kcgroup ^ g(r)), g(r)=(r>>1)&3, 16B chunks.
// Staged via global_load_lds (lane*16B dest), swizzle applied on global source col.
__global__ __launch_bounds__(256) void gemm1(const u16* __restrict__ A,
                                             const u16* __restrict__ Bt,
                                             u16* __restrict__ Xi) {
  __shared__ u16 As[128 * 32];
  __shared__ u16 Bs[128 * 32];
  const int tid = threadIdx.x;
  const int wave = tid >> 6, lane = tid & 63;
  const int quad = lane >> 4, l16 = lane & 15;
  const int nbase = blockIdx.x * 128;   // x = N so co-resident blocks share A stripe
  const int mbase = blockIdx.y * 128;
  const int wm = (wave & 1) * 64, wn = (wave >> 1) * 64;

  f32x4 acc[4][4];
#pragma unroll
  for (int i = 0; i < 4; i++)
#pragma unroll
    for (int j = 0; j < 4; j++)
#pragma unroll
      for (int r = 0; r < 4; r++) acc[i][j][r] = 0.0f;

  // staging source: thread tid -> segment row r0=tid>>2, kc group (tid&3)^g(r0)
  const int r0 = tid >> 2;
  const int kcg = ((tid & 3) ^ ((r0 >> 1) & 3)) * 8;
  const u16* Aptr = A + (long)(mbase + r0) * K1 + kcg;
  const u16* Bptr = Bt + (long)(nbase + r0) * K1 + kcg;
  u16* ldsA0 = As + tid * 8;
  u16* ldsA1 = As + 2048 + tid * 8;
  u16* ldsB0 = Bs + tid * 8;
  u16* ldsB1 = Bs + 2048 + tid * 8;

  // fragment pointers (loop-invariant): row*32 + (quad^g(row))*8
  const s16x8* apf[4];
  const s16x8* bpf[4];
#pragma unroll
  for (int i = 0; i < 4; i++) {
    int ra = wm + i * 16 + l16;
    int rb = wn + i * 16 + l16;
    apf[i] = (const s16x8*)(As + ra * 32 + ((quad ^ ((ra >> 1) & 3)) << 3));
    bpf[i] = (const s16x8*)(Bs + rb * 32 + ((quad ^ ((rb >> 1) & 3)) << 3));
  }

  for (int k0 = 0; k0 < K1; k0 += 32) {
    __syncthreads();
    gld16(Aptr + k0, ldsA0);
    gld16(Aptr + 64 * K1 + k0, ldsA1);
    gld16(Bptr + k0, ldsB0);
    gld16(Bptr + 64 * K1 + k0, ldsB1);
    __syncthreads();
    s16x8 af[4], bfr[4];
#pragma unroll
    for (int i = 0; i < 4; i++) { af[i] = *apf[i]; bfr[i] = *bpf[i]; }
#pragma unroll
    for (int mi = 0; mi < 4; mi++)
#pragma unroll
      for (int ni = 0; ni < 4; ni++)
        acc[mi][ni] = __builtin_amdgcn_mfma_f32_16x16x32_bf16(af[mi], bfr[ni], acc[mi][ni], 0, 0, 0);
  }

#pragma unroll
  for (int mi = 0; mi < 4; mi++) {
#pragma unroll
    for (int rr = 0; rr < 4; rr++) {
      int row = mbase + wm + mi * 16 + quad * 4 + rr;
      u16* orow = Xi + (long)row * N1 + nbase + wn;
#pragma unroll
      for (int ni = 0; ni < 4; ni++)
        orow[ni * 16 + l16] = f2bf(acc[mi][ni][rr]);
    }
  }
}

// ---- gate1: h1 = (1-z)*tanh(xh + b0h + r*b1h) ----
__global__ void gate1(const u16* __restrict__ Xi, const float* __restrict__ bias,
                      u16* __restrict__ H1) {
  int t = blockIdx.x * 256 + threadIdx.x;  // NB*384/8 tasks
  int row = t / 48;
  int ug = (t - row * 48) * 8;
  const u16* xir = Xi + (long)row * N1;
  union { uint4 v; u16 u[8]; } uz, ur, uh, o;
  uz.v = *(const uint4*)(xir + ug);
  ur.v = *(const uint4*)(xir + 384 + ug);
  uh.v = *(const uint4*)(xir + 768 + ug);
#pragma unroll
  for (int j = 0; j < 8; j++) {
    int u = ug + j;
    float z  = sigmoidf_(bf2f(uz.u[j]) + bias[u] + bias[1152 + u]);
    float rg = sigmoidf_(bf2f(ur.u[j]) + bias[384 + u] + bias[1152 + 384 + u]);
    float hc = tanhf_(bf2f(uh.u[j]) + bias[768 + u] + rg * bias[1152 + 768 + u]);
    o.u[j] = f2bf((1.0f - z) * hc);
  }
  *(uint4*)(H1 + (long)row * G1D + ug) = o.v;
}

// ---- GEMM2 + gates fused: H2(f32 NB x 16) from H1 @ W2t^T ----
__global__ __launch_bounds__(256) void gemm2(const u16* __restrict__ H1b,
                                             const u16* __restrict__ W2t,
                                             const float* __restrict__ bias2,
                                             float* __restrict__ H2) {
  __shared__ u16 As[128 * 32];
  __shared__ u16 Bs[48 * 32];
  const int tid = threadIdx.x;
  const int wave = tid >> 6, lane = tid & 63;
  const int quad = lane >> 4, l16 = lane & 15;
  const int mbase = blockIdx.x * 128;

  f32x4 acc[2][3];
#pragma unroll
  for (int i = 0; i < 2; i++)
#pragma unroll
    for (int j = 0; j < 3; j++)
#pragma unroll
      for (int r = 0; r < 4; r++) acc[i][j][r] = 0.0f;

  const int r0 = tid >> 2, kc = (tid & 3) * 8;
  const u16* Aptr = H1b + (long)(mbase + r0) * K2 + kc;

  for (int k0 = 0; k0 < K2; k0 += 32) {
    uint4 a0 = *(const uint4*)(Aptr + k0);
    uint4 a1 = *(const uint4*)(Aptr + 64 * K2 + k0);
    uint4 bv;
    if (tid < 192) bv = *(const uint4*)(W2t + r0 * K2 + k0 + kc);
    __syncthreads();
    *(uint4*)(&As[r0 * 32 + kc]) = a0;
    *(uint4*)(&As[(64 + r0) * 32 + kc]) = a1;
    if (tid < 192) *(uint4*)(&Bs[r0 * 32 + kc]) = bv;
    __syncthreads();
    s16x8 af[2], bfr[3];
#pragma unroll
    for (int mi = 0; mi < 2; mi++)
      af[mi] = *(const s16x8*)(&As[(wave * 32 + mi * 16 + l16) * 32 + quad * 8]);
#pragma unroll
    for (int ni = 0; ni < 3; ni++)
      bfr[ni] = *(const s16x8*)(&Bs[(ni * 16 + l16) * 32 + quad * 8]);
#pragma unroll
    for (int mi = 0; mi < 2; mi++)
#pragma unroll
      for (int ni = 0; ni < 3; ni++)
        acc[mi][ni] = __builtin_amdgcn_mfma_f32_16x16x32_bf16(af[mi], bfr[ni], acc[mi][ni], 0, 0, 0);
  }

  const int u = l16;
  const float b0z = bias2[u],      b1z = bias2[48 + u];
  const float b0r = bias2[16 + u], b1r = bias2[64 + u];
  const float b0h = bias2[32 + u], b1h = bias2[80 + u];
#pragma unroll
  for (int mi = 0; mi < 2; mi++) {
#pragma unroll
    for (int rr = 0; rr < 4; rr++) {
      int row = mbase + wave * 32 + mi * 16 + quad * 4 + rr;
      float z  = sigmoidf_(acc[mi][0][rr] + b0z + b1z);
      float rg = sigmoidf_(acc[mi][1][rr] + b0r + b1r);
      float hc = tanhf_(acc[mi][2][rr] + b0h + rg * b1h);
      H2[row * 16 + u] = (1.0f - z) * hc;
    }
  }
}

// ---- FC + softmax: one wave per row ----
__global__ __launch_bounds__(256) void fc_softmax(const float* __restrict__ H2,
                                                  const float* __restrict__ w1,
                                                  const float* __restrict__ fb1,
                                                  const float* __restrict__ w2,
                                                  const float* __restrict__ fb2,
                                                  const float* __restrict__ g1,
                                                  const float* __restrict__ g2,
                                                  float* __restrict__ out) {
  int row = blockIdx.x * 4 + (threadIdx.x >> 6);
  int lane = threadIdx.x & 63;
  const float* h2r = H2 + row * 16;
  float h[16];
#pragma unroll
  for (int uu = 0; uu < 16; uu++) h[uu] = h2r[uu];
  float e[4];
  float mx = -1e30f;
#pragma unroll
  for (int i = 0; i < 4; i++) {
    int c = i * 64 + lane;
    float a1 = fb1[c], a2 = fb2[c];
#pragma unroll
    for (int uu = 0; uu < 16; uu++) {
      a1 = fmaf(h[uu], w1[uu * 256 + c], a1);
      a2 = fmaf(h[uu], w2[uu * 256 + c], a2);
    }
    float d = g1[c] * tanhf_(a1) + g2[c] * tanhf_(a2);
    e[i] = d;
    mx = fmaxf(mx, d);
  }
#pragma unroll
  for (int off = 32; off >= 1; off >>= 1) mx = fmaxf(mx, __shfl_xor(mx, off, 64));
  float s = 0.0f;
#pragma unroll
  for (int i = 0; i < 4; i++) { e[i] = __expf(e[i] - mx); s += e[i]; }
#pragma unroll
  for (int off = 32; off >= 1; off >>= 1) s += __shfl_xor(s, off, 64);
  float inv = 1.0f / s;
  float* orow = out + (long)row * 256;
#pragma unroll
  for (int i = 0; i < 4; i++) orow[i * 64 + lane] = e[i] * inv;
}

extern "C" void kernel_launch(void* const* d_in, const int* in_sizes, int n_in,
                              void* d_out, int out_size, void* d_ws, size_t ws_size,
                              hipStream_t stream) {
  const float* x1   = (const float*)d_in[0];
  const float* x2   = (const float*)d_in[1];
  const float* w1k  = (const float*)d_in[2];   // gru1_kernel (512 x 1152)
  const float* b1g  = (const float*)d_in[4];   // gru1_bias (2 x 1152)
  const float* w2k  = (const float*)d_in[5];   // gru2_kernel (384 x 48)
  const float* b2g  = (const float*)d_in[7];   // gru2_bias (2 x 48)
  const float* fcw1 = (const float*)d_in[8];
  const float* fcb1 = (const float*)d_in[9];
  const float* fcw2 = (const float*)d_in[10];
  const float* fcb2 = (const float*)d_in[11];
  const float* fcg1 = (const float*)d_in[12];
  const float* fcg2 = (const float*)d_in[13];
  float* out = (float*)d_out;

  char* ws = (char*)d_ws;
  u16* Abf = (u16*)(ws + 0);            // 65536*512*2   = 67108864
  u16* W1t = (u16*)(ws + 67108864);     // 1152*512*2    = 1179648
  u16* Xi  = (u16*)(ws + 68288512);     // 65536*1152*2  = 150994944
  u16* H1  = (u16*)(ws + 219283456);    // 65536*384*2   = 50331648
  u16* W2t = (u16*)(ws + 269615104);    // 48*384*2      = 36864
  float* H2 = (float*)(ws + 269651968); // 65536*16*4    = 4194304

  hipLaunchKernelGGL(prep_a, dim3(16384), dim3(256), 0, stream, x1, x2, Abf);
  hipLaunchKernelGGL(prep_wt1, dim3(18, 8), dim3(256), 0, stream, w1k, W1t);
  hipLaunchKernelGGL(prep_wt, dim3(48), dim3(64), 0, stream, w2k, W2t, 384, 48);
  hipLaunchKernelGGL(gemm1, dim3(9, 512), dim3(256), 0, stream, Abf, W1t, Xi);
  hipLaunchKernelGGL(gate1, dim3(12288), dim3(256), 0, stream, Xi, b1g, H1);
  hipLaunchKernelGGL(gemm2, dim3(512), dim3(256), 0, stream, H1, W2t, b2g, H2);
  hipLaunchKernelGGL(fc_softmax, dim3(16384), dim3(256), 0, stream, H2,
                     fcw1, fcb1, fcw2, fcb2, fcg1, fcg2, out);
}

// Round 3
// 426.579 us; speedup vs baseline: 1.1066x; 1.1017x over previous
//
#include <hip/hip_runtime.h>

typedef unsigned short u16;
typedef unsigned int   u32;
typedef float f32x4 __attribute__((ext_vector_type(4)));
typedef short s16x8 __attribute__((ext_vector_type(8)));

#define NB    65536
#define K1    512
#define N1    1152
#define G1D   384
#define K2    384
#define N2    48
#define G2D   16
#define NL    256

__device__ inline u16 f2bf(float f) {
  u32 u = __float_as_uint(f);
  u += 0x7fffu + ((u >> 16) & 1u);
  return (u16)(u >> 16);
}
__device__ inline float bf2f(u16 h) { return __uint_as_float(((u32)h) << 16); }
__device__ inline float sigmoidf_(float x) { return 1.0f / (1.0f + __expf(-x)); }
__device__ inline float tanhf_(float x) {
  float e = __expf(2.0f * fabsf(x));
  float t = 1.0f - 2.0f / (e + 1.0f);
  return copysignf(t, x);
}

// async global->LDS, 16B per lane; LDS dest must be wave-uniform base + lane*16
__device__ inline void gld16(const u16* g, u16* l) {
  __builtin_amdgcn_global_load_lds(
      (const __attribute__((address_space(1))) void*)g,
      (__attribute__((address_space(3))) void*)l, 16, 0, 0);
}

// ---- prep: concat x1|x2 -> bf16 A (NB x 512) ----
__global__ void prep_a(const float* __restrict__ x1, const float* __restrict__ x2,
                       u16* __restrict__ Abf) {
  int t = blockIdx.x * 256 + threadIdx.x;   // 8 elems/thread
  int i = t * 8;
  int row = i >> 9, col = i & 511;
  const float* src = (col < 384) ? (x1 + row * 384 + col) : (x2 + row * 128 + (col - 384));
  float4 v0 = ((const float4*)src)[0];
  float4 v1 = ((const float4*)src)[1];
  union { uint4 v; u16 u[8]; } o;
  o.u[0] = f2bf(v0.x); o.u[1] = f2bf(v0.y); o.u[2] = f2bf(v0.z); o.u[3] = f2bf(v0.w);
  o.u[4] = f2bf(v1.x); o.u[5] = f2bf(v1.y); o.u[6] = f2bf(v1.z); o.u[7] = f2bf(v1.w);
  *(uint4*)(Abf + i) = o.v;
}

// ---- prep: coalesced tile-transpose W1 [512][1152] f32 -> W1t [1152][512] bf16 ----
__global__ __launch_bounds__(256) void prep_wt1(const float* __restrict__ w,
                                                u16* __restrict__ wt) {
  __shared__ float tile[64][65];
  const int nt = blockIdx.x * 64;   // 18
  const int kt = blockIdx.y * 64;   // 8
  const int tr = threadIdx.x >> 4;
  const int tc = (threadIdx.x & 15) * 4;
#pragma unroll
  for (int p = 0; p < 4; p++) {
    int k = kt + p * 16 + tr;
    float4 v = *(const float4*)(w + (long)k * N1 + nt + tc);
    tile[p * 16 + tr][tc + 0] = v.x;
    tile[p * 16 + tr][tc + 1] = v.y;
    tile[p * 16 + tr][tc + 2] = v.z;
    tile[p * 16 + tr][tc + 3] = v.w;
  }
  __syncthreads();
  const int nl = threadIdx.x >> 3;        // 0..31
  const int kc = (threadIdx.x & 7) * 8;
#pragma unroll
  for (int p = 0; p < 2; p++) {
    int n = nl + p * 32;
    union { uint4 v; u16 u[8]; } o;
#pragma unroll
    for (int j = 0; j < 8; j++) o.u[j] = f2bf(tile[kc + j][n]);
    *(uint4*)(wt + (long)(nt + n) * K1 + kt + kc) = o.v;
  }
}

// ---- prep: small transpose+cast weight w[K][N] -> wt[N][K] bf16 (W2) ----
__global__ void prep_wt(const float* __restrict__ w, u16* __restrict__ wt, int K, int N) {
  int n = blockIdx.x;
  int k0 = threadIdx.x * 8;
  if (k0 >= K) return;
  union { uint4 v; u16 u[8]; } o;
#pragma unroll
  for (int j = 0; j < 8; j++) o.u[j] = f2bf(w[(k0 + j) * N + n]);
  *(uint4*)(wt + n * K + k0) = o.v;
}

// ---- FUSED GEMM1 + gates: H1 = gru1_gates(A @ W1t^T) ----
// Block computes a 128-row x 64-ucol tile of h1, holding z/r/h accumulators
// simultaneously (gate g's B-rows are W1t rows g*384 + u).
// Waves 2x2: wm=(wave&1)*64, wu=(wave>>1)*32; per wave 4x2 frags per gate.
__global__ __launch_bounds__(256) void gemm1gate(const u16* __restrict__ A,
                                                 const u16* __restrict__ Bt,
                                                 const float* __restrict__ bias,
                                                 u16* __restrict__ H1) {
  __shared__ u16 As[128 * 32];        // 8 KB
  __shared__ u16 Bs[3][64 * 32];      // 12 KB
  const int tid = threadIdx.x;
  const int wave = tid >> 6, lane = tid & 63;
  const int quad = lane >> 4, l16 = lane & 15;
  const int ucbase = blockIdx.x * 64;   // 0..5 within 384
  const int mbase = blockIdx.y * 128;
  const int wm = (wave & 1) * 64, wu = (wave >> 1) * 32;

  f32x4 acc[3][4][2];
#pragma unroll
  for (int g = 0; g < 3; g++)
#pragma unroll
    for (int i = 0; i < 4; i++)
#pragma unroll
      for (int j = 0; j < 2; j++)
#pragma unroll
        for (int r = 0; r < 4; r++) acc[g][i][j][r] = 0.0f;

  // staging: thread -> row r0=tid>>2, kc group swizzled by (r0>>1)&3
  const int r0 = tid >> 2;
  const int kcg = ((tid & 3) ^ ((r0 >> 1) & 3)) * 8;
  const u16* Aptr = A + (long)(mbase + r0) * K1 + kcg;
  const u16* Bptr0 = Bt + (long)(0 * G1D + ucbase + r0) * K1 + kcg;
  const u16* Bptr1 = Bt + (long)(1 * G1D + ucbase + r0) * K1 + kcg;
  const u16* Bptr2 = Bt + (long)(2 * G1D + ucbase + r0) * K1 + kcg;
  u16* ldsA0 = As + tid * 8;
  u16* ldsA1 = As + 2048 + tid * 8;
  u16* ldsB0 = Bs[0] + tid * 8;
  u16* ldsB1 = Bs[1] + tid * 8;
  u16* ldsB2 = Bs[2] + tid * 8;

  // fragment pointers (loop-invariant)
  const s16x8* apf[4];
#pragma unroll
  for (int i = 0; i < 4; i++) {
    int ra = wm + i * 16 + l16;
    apf[i] = (const s16x8*)(As + ra * 32 + ((quad ^ ((ra >> 1) & 3)) << 3));
  }
  const s16x8* bpf[3][2];
#pragma unroll
  for (int g = 0; g < 3; g++)
#pragma unroll
    for (int j = 0; j < 2; j++) {
      int rb = wu + j * 16 + l16;
      bpf[g][j] = (const s16x8*)(Bs[g] + rb * 32 + ((quad ^ ((rb >> 1) & 3)) << 3));
    }

  for (int k0 = 0; k0 < K1; k0 += 32) {
    __syncthreads();
    gld16(Aptr + k0, ldsA0);
    gld16(Aptr + 64 * K1 + k0, ldsA1);
    gld16(Bptr0 + k0, ldsB0);
    gld16(Bptr1 + k0, ldsB1);
    gld16(Bptr2 + k0, ldsB2);
    __syncthreads();
    s16x8 af[4];
#pragma unroll
    for (int i = 0; i < 4; i++) af[i] = *apf[i];
#pragma unroll
    for (int g = 0; g < 3; g++) {
      s16x8 bf0 = *bpf[g][0];
      s16x8 bf1 = *bpf[g][1];
#pragma unroll
      for (int mi = 0; mi < 4; mi++) {
        acc[g][mi][0] = __builtin_amdgcn_mfma_f32_16x16x32_bf16(af[mi], bf0, acc[g][mi][0], 0, 0, 0);
        acc[g][mi][1] = __builtin_amdgcn_mfma_f32_16x16x32_bf16(af[mi], bf1, acc[g][mi][1], 0, 0, 0);
      }
    }
  }

  // epilogue: gates
#pragma unroll
  for (int j = 0; j < 2; j++) {
    int u = ucbase + wu + j * 16 + l16;
    float bz = bias[u] + bias[1152 + u];
    float br = bias[384 + u] + bias[1536 + u];
    float bh0 = bias[768 + u];
    float bh1 = bias[1920 + u];
#pragma unroll
    for (int mi = 0; mi < 4; mi++) {
#pragma unroll
      for (int rr = 0; rr < 4; rr++) {
        int row = mbase + wm + mi * 16 + quad * 4 + rr;
        float z  = sigmoidf_(acc[0][mi][j][rr] + bz);
        float rg = sigmoidf_(acc[1][mi][j][rr] + br);
        float hc = tanhf_(acc[2][mi][j][rr] + bh0 + rg * bh1);
        H1[(long)row * G1D + u] = f2bf((1.0f - z) * hc);
      }
    }
  }
}

// ---- GEMM2 + gates fused: H2(f32 NB x 16) from H1 @ W2t^T ----
__global__ __launch_bounds__(256) void gemm2(const u16* __restrict__ H1b,
                                             const u16* __restrict__ W2t,
                                             const float* __restrict__ bias2,
                                             float* __restrict__ H2) {
  __shared__ u16 As[128 * 32];
  __shared__ u16 Bs[48 * 32];
  const int tid = threadIdx.x;
  const int wave = tid >> 6, lane = tid & 63;
  const int quad = lane >> 4, l16 = lane & 15;
  const int mbase = blockIdx.x * 128;

  f32x4 acc[2][3];
#pragma unroll
  for (int i = 0; i < 2; i++)
#pragma unroll
    for (int j = 0; j < 3; j++)
#pragma unroll
      for (int r = 0; r < 4; r++) acc[i][j][r] = 0.0f;

  const int r0 = tid >> 2, kc = (tid & 3) * 8;
  const u16* Aptr = H1b + (long)(mbase + r0) * K2 + kc;

  for (int k0 = 0; k0 < K2; k0 += 32) {
    uint4 a0 = *(const uint4*)(Aptr + k0);
    uint4 a1 = *(const uint4*)(Aptr + 64 * K2 + k0);
    uint4 bv;
    if (tid < 192) bv = *(const uint4*)(W2t + r0 * K2 + k0 + kc);
    __syncthreads();
    *(uint4*)(&As[r0 * 32 + kc]) = a0;
    *(uint4*)(&As[(64 + r0) * 32 + kc]) = a1;
    if (tid < 192) *(uint4*)(&Bs[r0 * 32 + kc]) = bv;
    __syncthreads();
    s16x8 af[2], bfr[3];
#pragma unroll
    for (int mi = 0; mi < 2; mi++)
      af[mi] = *(const s16x8*)(&As[(wave * 32 + mi * 16 + l16) * 32 + quad * 8]);
#pragma unroll
    for (int ni = 0; ni < 3; ni++)
      bfr[ni] = *(const s16x8*)(&Bs[(ni * 16 + l16) * 32 + quad * 8]);
#pragma unroll
    for (int mi = 0; mi < 2; mi++)
#pragma unroll
      for (int ni = 0; ni < 3; ni++)
        acc[mi][ni] = __builtin_amdgcn_mfma_f32_16x16x32_bf16(af[mi], bfr[ni], acc[mi][ni], 0, 0, 0);
  }

  const int u = l16;
  const float b0z = bias2[u],      b1z = bias2[48 + u];
  const float b0r = bias2[16 + u], b1r = bias2[64 + u];
  const float b0h = bias2[32 + u], b1h = bias2[80 + u];
#pragma unroll
  for (int mi = 0; mi < 2; mi++) {
#pragma unroll
    for (int rr = 0; rr < 4; rr++) {
      int row = mbase + wave * 32 + mi * 16 + quad * 4 + rr;
      float z  = sigmoidf_(acc[mi][0][rr] + b0z + b1z);
      float rg = sigmoidf_(acc[mi][1][rr] + b0r + b1r);
      float hc = tanhf_(acc[mi][2][rr] + b0h + rg * b1h);
      H2[row * 16 + u] = (1.0f - z) * hc;
    }
  }
}

// ---- FC + softmax: one wave per row ----
__global__ __launch_bounds__(256) void fc_softmax(const float* __restrict__ H2,
                                                  const float* __restrict__ w1,
                                                  const float* __restrict__ fb1,
                                                  const float* __restrict__ w2,
                                                  const float* __restrict__ fb2,
                                                  const float* __restrict__ g1,
                                                  const float* __restrict__ g2,
                                                  float* __restrict__ out) {
  int row = blockIdx.x * 4 + (threadIdx.x >> 6);
  int lane = threadIdx.x & 63;
  const float* h2r = H2 + row * 16;
  float h[16];
#pragma unroll
  for (int uu = 0; uu < 16; uu++) h[uu] = h2r[uu];
  float e[4];
  float mx = -1e30f;
#pragma unroll
  for (int i = 0; i < 4; i++) {
    int c = i * 64 + lane;
    float a1 = fb1[c], a2 = fb2[c];
#pragma unroll
    for (int uu = 0; uu < 16; uu++) {
      a1 = fmaf(h[uu], w1[uu * 256 + c], a1);
      a2 = fmaf(h[uu], w2[uu * 256 + c], a2);
    }
    float d = g1[c] * tanhf_(a1) + g2[c] * tanhf_(a2);
    e[i] = d;
    mx = fmaxf(mx, d);
  }
#pragma unroll
  for (int off = 32; off >= 1; off >>= 1) mx = fmaxf(mx, __shfl_xor(mx, off, 64));
  float s = 0.0f;
#pragma unroll
  for (int i = 0; i < 4; i++) { e[i] = __expf(e[i] - mx); s += e[i]; }
#pragma unroll
  for (int off = 32; off >= 1; off >>= 1) s += __shfl_xor(s, off, 64);
  float inv = 1.0f / s;
  float* orow = out + (long)row * 256;
#pragma unroll
  for (int i = 0; i < 4; i++) orow[i * 64 + lane] = e[i] * inv;
}

extern "C" void kernel_launch(void* const* d_in, const int* in_sizes, int n_in,
                              void* d_out, int out_size, void* d_ws, size_t ws_size,
                              hipStream_t stream) {
  const float* x1   = (const float*)d_in[0];
  const float* x2   = (const float*)d_in[1];
  const float* w1k  = (const float*)d_in[2];   // gru1_kernel (512 x 1152)
  const float* b1g  = (const float*)d_in[4];   // gru1_bias (2 x 1152)
  const float* w2k  = (const float*)d_in[5];   // gru2_kernel (384 x 48)
  const float* b2g  = (const float*)d_in[7];   // gru2_bias (2 x 48)
  const float* fcw1 = (const float*)d_in[8];
  const float* fcb1 = (const float*)d_in[9];
  const float* fcw2 = (const float*)d_in[10];
  const float* fcb2 = (const float*)d_in[11];
  const float* fcg1 = (const float*)d_in[12];
  const float* fcg2 = (const float*)d_in[13];
  float* out = (float*)d_out;

  char* ws = (char*)d_ws;
  u16* Abf = (u16*)(ws + 0);            // 65536*512*2   = 67108864
  u16* W1t = (u16*)(ws + 67108864);     // 1152*512*2    = 1179648
  u16* H1  = (u16*)(ws + 68288512);     // 65536*384*2   = 50331648
  u16* W2t = (u16*)(ws + 118620160);    // 48*384*2      = 36864
  float* H2 = (float*)(ws + 118657024); // 65536*16*4    = 4194304

  hipLaunchKernelGGL(prep_a, dim3(16384), dim3(256), 0, stream, x1, x2, Abf);
  hipLaunchKernelGGL(prep_wt1, dim3(18, 8), dim3(256), 0, stream, w1k, W1t);
  hipLaunchKernelGGL(prep_wt, dim3(48), dim3(64), 0, stream, w2k, W2t, 384, 48);
  hipLaunchKernelGGL(gemm1gate, dim3(6, 512), dim3(256), 0, stream, Abf, W1t, b1g, H1);
  hipLaunchKernelGGL(gemm2, dim3(512), dim3(256), 0, stream, H1, W2t, b2g, H2);
  hipLaunchKernelGGL(fc_softmax, dim3(16384), dim3(256), 0, stream, H2,
                     fcw1, fcb1, fcw2, fcb2, fcg1, fcg2, out);
}

// Round 4
// 385.207 us; speedup vs baseline: 1.2254x; 1.1074x over previous
//
#include <hip/hip_runtime.h>

typedef unsigned short u16;
typedef unsigned int   u32;
typedef float f32x4 __attribute__((ext_vector_type(4)));
typedef short s16x8 __attribute__((ext_vector_type(8)));

#define NB    65536
#define K1    512
#define N1    1152
#define G1D   384
#define K2    384
#define G2D   16
#define NL    256

__device__ inline u16 f2bf(float f) {
  u32 u = __float_as_uint(f);
  u += 0x7fffu + ((u >> 16) & 1u);
  return (u16)(u >> 16);
}
__device__ inline float bf2f(u16 h) { return __uint_as_float(((u32)h) << 16); }
__device__ inline float sigmoidf_(float x) { return 1.0f / (1.0f + __expf(-x)); }
__device__ inline float tanhf_(float x) {
  float e = __expf(2.0f * fabsf(x));
  float t = 1.0f - 2.0f / (e + 1.0f);
  return copysignf(t, x);
}

// async global->LDS, 16B per lane; LDS dest must be wave-uniform base + lane*16
__device__ inline void gld16(const u16* g, u16* l) {
  __builtin_amdgcn_global_load_lds(
      (const __attribute__((address_space(1))) void*)g,
      (__attribute__((address_space(3))) void*)l, 16, 0, 0);
}

// ---- prep: concat x1|x2 -> bf16 A (NB x 512) ----
__global__ void prep_a(const float* __restrict__ x1, const float* __restrict__ x2,
                       u16* __restrict__ Abf) {
  int t = blockIdx.x * 256 + threadIdx.x;   // 8 elems/thread
  int i = t * 8;
  int row = i >> 9, col = i & 511;
  const float* src = (col < 384) ? (x1 + row * 384 + col) : (x2 + row * 128 + (col - 384));
  float4 v0 = ((const float4*)src)[0];
  float4 v1 = ((const float4*)src)[1];
  union { uint4 v; u16 u[8]; } o;
  o.u[0] = f2bf(v0.x); o.u[1] = f2bf(v0.y); o.u[2] = f2bf(v0.z); o.u[3] = f2bf(v0.w);
  o.u[4] = f2bf(v1.x); o.u[5] = f2bf(v1.y); o.u[6] = f2bf(v1.z); o.u[7] = f2bf(v1.w);
  *(uint4*)(Abf + i) = o.v;
}

// ---- prep: coalesced tile-transpose W1 [512][1152] f32 -> W1t [1152][512] bf16 ----
__global__ __launch_bounds__(256) void prep_wt1(const float* __restrict__ w,
                                                u16* __restrict__ wt) {
  __shared__ float tile[64][65];
  const int nt = blockIdx.x * 64;   // 18
  const int kt = blockIdx.y * 64;   // 8
  const int tr = threadIdx.x >> 4;
  const int tc = (threadIdx.x & 15) * 4;
#pragma unroll
  for (int p = 0; p < 4; p++) {
    int k = kt + p * 16 + tr;
    float4 v = *(const float4*)(w + (long)k * N1 + nt + tc);
    tile[p * 16 + tr][tc + 0] = v.x;
    tile[p * 16 + tr][tc + 1] = v.y;
    tile[p * 16 + tr][tc + 2] = v.z;
    tile[p * 16 + tr][tc + 3] = v.w;
  }
  __syncthreads();
  const int nl = threadIdx.x >> 3;        // 0..31
  const int kc = (threadIdx.x & 7) * 8;
#pragma unroll
  for (int p = 0; p < 2; p++) {
    int n = nl + p * 32;
    union { uint4 v; u16 u[8]; } o;
#pragma unroll
    for (int j = 0; j < 8; j++) o.u[j] = f2bf(tile[kc + j][n]);
    *(uint4*)(wt + (long)(nt + n) * K1 + kt + kc) = o.v;
  }
}

// ---- prep: small transpose+cast weight w[K][N] -> wt[N][K] bf16 (W2) ----
__global__ void prep_wt(const float* __restrict__ w, u16* __restrict__ wt, int K, int N) {
  int n = blockIdx.x;
  int k0 = threadIdx.x * 8;
  if (k0 >= K) return;
  union { uint4 v; u16 u[8]; } o;
#pragma unroll
  for (int j = 0; j < 8; j++) o.u[j] = f2bf(w[(k0 + j) * N + n]);
  *(uint4*)(wt + n * K + k0) = o.v;
}

// ---- FUSED GEMM1 + gates: H1 = gru1_gates(A @ W1t^T) ----
// XCD-swizzled 1D grid (3072 blocks): all 6 u-blocks of one m-stripe land on
// the same XCD consecutively, so the A-stripe is fetched once per XCD L2.
__global__ __launch_bounds__(256) void gemm1gate(const u16* __restrict__ A,
                                                 const u16* __restrict__ Bt,
                                                 const float* __restrict__ bias,
                                                 u16* __restrict__ H1) {
  __shared__ u16 As[128 * 32];        // 8 KB
  __shared__ u16 Bs[3][64 * 32];      // 12 KB
  const int tid = threadIdx.x;
  const int wave = tid >> 6, lane = tid & 63;
  const int quad = lane >> 4, l16 = lane & 15;

  // XCD swizzle: xcd = id&7 (round-robin dispatch), 64 m-stripes per XCD,
  // 6 consecutive u-blocks per stripe.
  const int id = blockIdx.x;
  const int xcd = id & 7;
  const int s = id >> 3;          // 0..383
  const int sd6 = s / 6;          // 0..63
  const int ublk = s - sd6 * 6;   // 0..5
  const int mbase = (xcd * 64 + sd6) * 128;
  const int ucbase = ublk * 64;

  const int wm = (wave & 1) * 64, wu = (wave >> 1) * 32;

  f32x4 acc[3][4][2];
#pragma unroll
  for (int g = 0; g < 3; g++)
#pragma unroll
    for (int i = 0; i < 4; i++)
#pragma unroll
      for (int j = 0; j < 2; j++)
#pragma unroll
        for (int r = 0; r < 4; r++) acc[g][i][j][r] = 0.0f;

  // staging: thread -> row r0=tid>>2, kc group swizzled by (r0>>1)&3
  const int r0 = tid >> 2;
  const int kcg = ((tid & 3) ^ ((r0 >> 1) & 3)) * 8;
  const u16* Aptr = A + (long)(mbase + r0) * K1 + kcg;
  const u16* Bptr0 = Bt + (long)(0 * G1D + ucbase + r0) * K1 + kcg;
  const u16* Bptr1 = Bt + (long)(1 * G1D + ucbase + r0) * K1 + kcg;
  const u16* Bptr2 = Bt + (long)(2 * G1D + ucbase + r0) * K1 + kcg;
  u16* ldsA0 = As + tid * 8;
  u16* ldsA1 = As + 2048 + tid * 8;
  u16* ldsB0 = Bs[0] + tid * 8;
  u16* ldsB1 = Bs[1] + tid * 8;
  u16* ldsB2 = Bs[2] + tid * 8;

  // fragment pointers (loop-invariant)
  const s16x8* apf[4];
#pragma unroll
  for (int i = 0; i < 4; i++) {
    int ra = wm + i * 16 + l16;
    apf[i] = (const s16x8*)(As + ra * 32 + ((quad ^ ((ra >> 1) & 3)) << 3));
  }
  const s16x8* bpf[3][2];
#pragma unroll
  for (int g = 0; g < 3; g++)
#pragma unroll
    for (int j = 0; j < 2; j++) {
      int rb = wu + j * 16 + l16;
      bpf[g][j] = (const s16x8*)(Bs[g] + rb * 32 + ((quad ^ ((rb >> 1) & 3)) << 3));
    }

  for (int k0 = 0; k0 < K1; k0 += 32) {
    __syncthreads();
    gld16(Aptr + k0, ldsA0);
    gld16(Aptr + 64 * K1 + k0, ldsA1);
    gld16(Bptr0 + k0, ldsB0);
    gld16(Bptr1 + k0, ldsB1);
    gld16(Bptr2 + k0, ldsB2);
    __syncthreads();
    s16x8 af[4];
#pragma unroll
    for (int i = 0; i < 4; i++) af[i] = *apf[i];
#pragma unroll
    for (int g = 0; g < 3; g++) {
      s16x8 bf0 = *bpf[g][0];
      s16x8 bf1 = *bpf[g][1];
#pragma unroll
      for (int mi = 0; mi < 4; mi++) {
        acc[g][mi][0] = __builtin_amdgcn_mfma_f32_16x16x32_bf16(af[mi], bf0, acc[g][mi][0], 0, 0, 0);
        acc[g][mi][1] = __builtin_amdgcn_mfma_f32_16x16x32_bf16(af[mi], bf1, acc[g][mi][1], 0, 0, 0);
      }
    }
  }

  // epilogue: gates
#pragma unroll
  for (int j = 0; j < 2; j++) {
    int u = ucbase + wu + j * 16 + l16;
    float bz = bias[u] + bias[1152 + u];
    float br = bias[384 + u] + bias[1536 + u];
    float bh0 = bias[768 + u];
    float bh1 = bias[1920 + u];
#pragma unroll
    for (int mi = 0; mi < 4; mi++) {
#pragma unroll
      for (int rr = 0; rr < 4; rr++) {
        int row = mbase + wm + mi * 16 + quad * 4 + rr;
        float z  = sigmoidf_(acc[0][mi][j][rr] + bz);
        float rg = sigmoidf_(acc[1][mi][j][rr] + br);
        float hc = tanhf_(acc[2][mi][j][rr] + bh0 + rg * bh1);
        H1[(long)row * G1D + u] = f2bf((1.0f - z) * hc);
      }
    }
  }
}

// ---- FUSED GEMM2 + gates + FC + softmax ----
// Phase 1: gemm2 gates -> h2 (128 x 16) kept in LDS (fp32, padded stride 17).
// Phase 2: wave w owns rows w*32..w*32+31; per row, 64 lanes x 4 cols each,
// exact softmax via wave shuffles, coalesced out writes.
__global__ __launch_bounds__(256) void gemm2fc(const u16* __restrict__ H1b,
                                               const u16* __restrict__ W2t,
                                               const float* __restrict__ bias2,
                                               const float* __restrict__ w1,
                                               const float* __restrict__ fb1,
                                               const float* __restrict__ w2,
                                               const float* __restrict__ fb2,
                                               const float* __restrict__ g1,
                                               const float* __restrict__ g2,
                                               float* __restrict__ out) {
  __shared__ u16 As[128 * 32];      // 8 KB
  __shared__ u16 Bs[48 * 32];       // 3 KB
  __shared__ float h2s[128 * 17];   // 8.5 KB
  const int tid = threadIdx.x;
  const int wave = tid >> 6, lane = tid & 63;
  const int quad = lane >> 4, l16 = lane & 15;
  const int mbase = blockIdx.x * 128;

  f32x4 acc[2][3];
#pragma unroll
  for (int i = 0; i < 2; i++)
#pragma unroll
    for (int j = 0; j < 3; j++)
#pragma unroll
      for (int r = 0; r < 4; r++) acc[i][j][r] = 0.0f;

  const int r0 = tid >> 2, kc = (tid & 3) * 8;
  const u16* Aptr = H1b + (long)(mbase + r0) * K2 + kc;

  for (int k0 = 0; k0 < K2; k0 += 32) {
    uint4 a0 = *(const uint4*)(Aptr + k0);
    uint4 a1 = *(const uint4*)(Aptr + 64 * K2 + k0);
    uint4 bv;
    if (tid < 192) bv = *(const uint4*)(W2t + r0 * K2 + k0 + kc);
    __syncthreads();
    *(uint4*)(&As[r0 * 32 + kc]) = a0;
    *(uint4*)(&As[(64 + r0) * 32 + kc]) = a1;
    if (tid < 192) *(uint4*)(&Bs[r0 * 32 + kc]) = bv;
    __syncthreads();
    s16x8 af[2], bfr[3];
#pragma unroll
    for (int mi = 0; mi < 2; mi++)
      af[mi] = *(const s16x8*)(&As[(wave * 32 + mi * 16 + l16) * 32 + quad * 8]);
#pragma unroll
    for (int ni = 0; ni < 3; ni++)
      bfr[ni] = *(const s16x8*)(&Bs[(ni * 16 + l16) * 32 + quad * 8]);
#pragma unroll
    for (int mi = 0; mi < 2; mi++)
#pragma unroll
      for (int ni = 0; ni < 3; ni++)
        acc[mi][ni] = __builtin_amdgcn_mfma_f32_16x16x32_bf16(af[mi], bfr[ni], acc[mi][ni], 0, 0, 0);
  }

  {
    const int u = l16;
    const float b0z = bias2[u],      b1z = bias2[48 + u];
    const float b0r = bias2[16 + u], b1r = bias2[64 + u];
    const float b0h = bias2[32 + u], b1h = bias2[80 + u];
#pragma unroll
    for (int mi = 0; mi < 2; mi++) {
#pragma unroll
      for (int rr = 0; rr < 4; rr++) {
        int row_l = wave * 32 + mi * 16 + quad * 4 + rr;
        float z  = sigmoidf_(acc[mi][0][rr] + b0z + b1z);
        float rg = sigmoidf_(acc[mi][1][rr] + b0r + b1r);
        float hc = tanhf_(acc[mi][2][rr] + b0h + rg * b1h);
        h2s[row_l * 17 + u] = (1.0f - z) * hc;
      }
    }
  }
  __syncthreads();

  // Phase 2: fc + softmax, wave-per-row (32 rows per wave)
#pragma unroll 1
  for (int r = 0; r < 32; r++) {
    int row_l = wave * 32 + r;
    float h[16];
#pragma unroll
    for (int uu = 0; uu < 16; uu++) h[uu] = h2s[row_l * 17 + uu];
    float e[4];
    float mx = -1e30f;
#pragma unroll
    for (int i = 0; i < 4; i++) {
      int c = i * 64 + lane;
      float a1 = fb1[c], a2 = fb2[c];
#pragma unroll
      for (int uu = 0; uu < 16; uu++) {
        a1 = fmaf(h[uu], w1[uu * 256 + c], a1);
        a2 = fmaf(h[uu], w2[uu * 256 + c], a2);
      }
      float d = g1[c] * tanhf_(a1) + g2[c] * tanhf_(a2);
      e[i] = d;
      mx = fmaxf(mx, d);
    }
#pragma unroll
    for (int off = 32; off >= 1; off >>= 1) mx = fmaxf(mx, __shfl_xor(mx, off, 64));
    float sum = 0.0f;
#pragma unroll
    for (int i = 0; i < 4; i++) { e[i] = __expf(e[i] - mx); sum += e[i]; }
#pragma unroll
    for (int off = 32; off >= 1; off >>= 1) sum += __shfl_xor(sum, off, 64);
    float inv = 1.0f / sum;
    float* orow = out + (long)(mbase + row_l) * NL;
#pragma unroll
    for (int i = 0; i < 4; i++) orow[i * 64 + lane] = e[i] * inv;
  }
}

extern "C" void kernel_launch(void* const* d_in, const int* in_sizes, int n_in,
                              void* d_out, int out_size, void* d_ws, size_t ws_size,
                              hipStream_t stream) {
  const float* x1   = (const float*)d_in[0];
  const float* x2   = (const float*)d_in[1];
  const float* w1k  = (const float*)d_in[2];   // gru1_kernel (512 x 1152)
  const float* b1g  = (const float*)d_in[4];   // gru1_bias (2 x 1152)
  const float* w2k  = (const float*)d_in[5];   // gru2_kernel (384 x 48)
  const float* b2g  = (const float*)d_in[7];   // gru2_bias (2 x 48)
  const float* fcw1 = (const float*)d_in[8];
  const float* fcb1 = (const float*)d_in[9];
  const float* fcw2 = (const float*)d_in[10];
  const float* fcb2 = (const float*)d_in[11];
  const float* fcg1 = (const float*)d_in[12];
  const float* fcg2 = (const float*)d_in[13];
  float* out = (float*)d_out;

  char* ws = (char*)d_ws;
  u16* Abf = (u16*)(ws + 0);            // 65536*512*2   = 67108864
  u16* W1t = (u16*)(ws + 67108864);     // 1152*512*2    = 1179648
  u16* H1  = (u16*)(ws + 68288512);     // 65536*384*2   = 50331648
  u16* W2t = (u16*)(ws + 118620160);    // 48*384*2      = 36864

  hipLaunchKernelGGL(prep_a, dim3(16384), dim3(256), 0, stream, x1, x2, Abf);
  hipLaunchKernelGGL(prep_wt1, dim3(18, 8), dim3(256), 0, stream, w1k, W1t);
  hipLaunchKernelGGL(prep_wt, dim3(48), dim3(64), 0, stream, w2k, W2t, 384, 48);
  hipLaunchKernelGGL(gemm1gate, dim3(3072), dim3(256), 0, stream, Abf, W1t, b1g, H1);
  hipLaunchKernelGGL(gemm2fc, dim3(512), dim3(256), 0, stream, H1, W2t, b2g,
                     fcw1, fcb1, fcw2, fcb2, fcg1, fcg2, out);
}